// Round 8
// baseline (407.958 us; speedup 1.0000x reference)
//
#include <hip/hip_runtime.h>
#include <stdint.h>
#include <math.h>

#define DEV static __device__ __forceinline__

typedef __attribute__((ext_vector_type(8))) short bf16x8;
typedef __attribute__((ext_vector_type(4))) float f32x4;
typedef __attribute__((ext_vector_type(8))) unsigned short u16x8;

// ---------------- Threefry-2x32/20 (exact JAX schedule) ----------------
DEV uint32_t rotl32(uint32_t v, int d) { return (v << d) | (v >> (32 - d)); }

DEV void threefry2x32(uint32_t k0, uint32_t k1, uint32_t& x0, uint32_t& x1) {
  const uint32_t k2 = k0 ^ k1 ^ 0x1BD11BDAu;
  x0 += k0; x1 += k1;
#define TFR(R) { x0 += x1; x1 = rotl32(x1, R) ^ x0; }
  TFR(13) TFR(15) TFR(26) TFR(6)
  x0 += k1; x1 += k2 + 1u;
  TFR(17) TFR(29) TFR(16) TFR(24)
  x0 += k2; x1 += k0 + 2u;
  TFR(13) TFR(15) TFR(26) TFR(6)
  x0 += k0; x1 += k1 + 3u;
  TFR(17) TFR(29) TFR(16) TFR(24)
  x0 += k1; x1 += k2 + 4u;
  TFR(13) TFR(15) TFR(26) TFR(6)
  x0 += k2; x1 += k0 + 5u;
#undef TFR
}

// ---------------- erfinv (XLA f32 ErfInv, Giles 2012) ----------------
DEV float erfinv_f32(float x) {
  float w = -log1pf(-x * x);
  float p;
  if (w < 5.0f) {
    w -= 2.5f;
    p = 2.81022636e-08f;
    p = fmaf(p, w, 3.43273939e-07f);
    p = fmaf(p, w, -3.5233877e-06f);
    p = fmaf(p, w, -4.39150654e-06f);
    p = fmaf(p, w, 0.00021858087f);
    p = fmaf(p, w, -0.00125372503f);
    p = fmaf(p, w, -0.00417768164f);
    p = fmaf(p, w, 0.246640727f);
    p = fmaf(p, w, 1.50140941f);
  } else {
    w = sqrtf(w) - 3.0f;
    p = -0.000200214257f;
    p = fmaf(p, w, 0.000100950558f);
    p = fmaf(p, w, 0.00134934322f);
    p = fmaf(p, w, -0.00367342844f);
    p = fmaf(p, w, 0.00573950773f);
    p = fmaf(p, w, -0.0076224613f);
    p = fmaf(p, w, 0.00943887047f);
    p = fmaf(p, w, 1.00167406f);
    p = fmaf(p, w, 2.83297682f);
  }
  return p * x;
}

DEV float normal_from_bits(uint32_t bits) {
  float f = __uint_as_float((bits >> 9) | 0x3F800000u) - 1.0f;
  const float lo = -0.99999994f;            // nextafter(-1, 0) in f32
  float u = fmaf(f, 2.0f, lo);
  u = fmaxf(u, lo);
  return 1.41421356f * erfinv_f32(u);
}

DEV unsigned short f2bf(float f) {   // RTNE f32 -> bf16
  uint32_t u = __float_as_uint(f);
  uint32_t r = u + 0x7FFFu + ((u >> 16) & 1u);
  return (unsigned short)(r >> 16);
}

DEV float bf2f(uint32_t h) { return __uint_as_float(h << 16); }

// ---------------- CSR build ----------------
__global__ void count_kernel(const int* __restrict__ rows, const int* __restrict__ cols,
                             int* __restrict__ counts, int* __restrict__ degs, int E) {
  int e = blockIdx.x * blockDim.x + threadIdx.x;
  if (e < E) {
    int r = rows[e];
    atomicAdd(&counts[r], 1);
    if (r != cols[e]) atomicAdd(&degs[r], 1);
  }
}

__global__ void dinv_kernel(const int* __restrict__ degs, float* __restrict__ dinv, int N) {
  int i = blockIdx.x * blockDim.x + threadIdx.x;
  if (i < N) {
    int d = degs[i];
    dinv[i] = d > 0 ? rsqrtf((float)d) : 0.0f;
  }
}

#define SCAN_T 1024
__global__ __launch_bounds__(SCAN_T) void scan_kernel(const int* __restrict__ counts,
                                                      int* __restrict__ row_ptr,
                                                      int* __restrict__ cursor, int N) {
  __shared__ int sa[SCAN_T], sb[SCAN_T];
  const int t = threadIdx.x;
  const int CH = (N + SCAN_T - 1) / SCAN_T;
  int base = t * CH;
  int psum = 0;
  for (int k = 0; k < CH; ++k) {
    int idx = base + k;
    if (idx < N) psum += counts[idx];
  }
  sa[t] = psum;
  __syncthreads();
  int* src = sa; int* dst = sb;
  for (int off = 1; off < SCAN_T; off <<= 1) {
    int v = src[t];
    if (t >= off) v += src[t - off];
    dst[t] = v;
    __syncthreads();
    int* tmp = src; src = dst; dst = tmp;
  }
  int running = src[t] - psum;
  for (int k = 0; k < CH; ++k) {
    int idx = base + k;
    if (idx < N) {
      row_ptr[idx] = running;
      cursor[idx] = running;
      running += counts[idx];
    }
  }
  if (t == SCAN_T - 1) row_ptr[N] = running;
}

__global__ void fill_kernel(const int* __restrict__ rows, const int* __restrict__ cols,
                            const float* __restrict__ dinv, int* __restrict__ cursor,
                            float2* __restrict__ ecv, int E) {
  int e = blockIdx.x * blockDim.x + threadIdx.x;
  if (e < E) {
    int r = rows[e], c = cols[e];
    float w = (r != c) ? -dinv[r] * dinv[c] : 0.0f;
    int pos = atomicAdd(&cursor[r], 1);
    ecv[pos] = make_float2(__int_as_float(c), w);
  }
}

// ---------------- row loader: VEC floats from bf16 source ----------------
template <int VEC>
DEV void ldrow(const unsigned short* base, size_t off, float* v) {
  const unsigned short* p = base + off;
  if (VEC == 4) {
    uint2 u = *(const uint2*)p;
    v[0] = bf2f(u.x & 0xffffu); v[1] = bf2f(u.x >> 16);
    v[2] = bf2f(u.y & 0xffffu); v[3] = bf2f(u.y >> 16);
  } else {
    uint32_t u = *(const uint32_t*)p;
    v[0] = bf2f(u & 0xffffu); v[1] = bf2f(u >> 16);
  }
}

// ---------------- propagation: one wave per node, 8-edge unrolled gather ----------------
// SUB=0: outb = bf16(P x)
// SUB=1: outb = bf16(2*P x - xsub)
template <int VEC, int SUB>
__global__ __launch_bounds__(256) void gather_prop(
    const int* __restrict__ row_ptr, const float2* __restrict__ ecv,
    const unsigned short* __restrict__ xsrc, int sstride,
    const float* __restrict__ xsub, int substride,
    unsigned short* __restrict__ outb, int N, int F, int Fpad) {
  const int wave = threadIdx.x >> 6, lane = threadIdx.x & 63;
  const int node = blockIdx.x * 4 + wave;
  if (node >= N) return;
  const int f0 = lane * VEC;
  if (f0 >= Fpad) return;
  const bool live = (f0 + VEC) <= F;
  float acc[VEC] = {};
  if (live) {
    const int s = row_ptr[node], e = row_ptr[node + 1];
    int j = s;
    for (; j + 8 <= e; j += 8) {
      float2 cw[8];
      float vv[8][VEC];
#pragma unroll
      for (int q = 0; q < 8; ++q) cw[q] = ecv[j + q];
#pragma unroll
      for (int q = 0; q < 8; ++q)
        ldrow<VEC>(xsrc, (size_t)__float_as_int(cw[q].x) * sstride + f0, vv[q]);
#pragma unroll
      for (int q = 0; q < 8; ++q)
#pragma unroll
        for (int z = 0; z < VEC; ++z) acc[z] = fmaf(cw[q].y, vv[q][z], acc[z]);
    }
    for (; j < e; ++j) {
      float2 cw = ecv[j];
      float vv[VEC];
      ldrow<VEC>(xsrc, (size_t)__float_as_int(cw.x) * sstride + f0, vv);
#pragma unroll
      for (int z = 0; z < VEC; ++z) acc[z] = fmaf(cw.y, vv[z], acc[z]);
    }
    if (SUB) {
      const float* sb = xsub + (size_t)node * substride + f0;
#pragma unroll
      for (int z = 0; z < VEC; ++z) acc[z] = fmaf(2.0f, acc[z], -sb[z]);
    }
  }
  size_t ob = (size_t)node * Fpad + f0;
  if (VEC == 4) {
    uint2 u;
    u.x = (uint32_t)f2bf(acc[0]) | ((uint32_t)f2bf(acc[1]) << 16);
    u.y = (uint32_t)f2bf(acc[2]) | ((uint32_t)f2bf(acc[3]) << 16);
    *(uint2*)&outb[ob] = u;
  } else {
    uint32_t u = (uint32_t)f2bf(acc[0]) | ((uint32_t)f2bf(acc[1]) << 16);
    *(uint32_t*)&outb[ob] = u;
  }
}

// ---------------- weight transpose+convert: Wt[p][o][k] = bf16(W[p][k][o]) ----------------
__global__ void wtrans_kernel(const float* __restrict__ W, unsigned short* __restrict__ Wt,
                              int F, int Fpad, int O) {
  int idx = blockIdx.x * 256 + threadIdx.x;
  int total = 3 * O * Fpad;
  if (idx >= total) return;
  int k = idx % Fpad;
  int o = (idx / Fpad) % O;
  int p = idx / (Fpad * O);
  Wt[idx] = (k < F) ? f2bf(W[((size_t)p * F + k) * O + o]) : (unsigned short)0;
}

// ---------------- input convert: vb[i][k<96] = bf16(v[i][k<86]) ----------------
__global__ void vconv_kernel(const float* __restrict__ v, unsigned short* __restrict__ vb, int N) {
  int i = blockIdx.x * 256 + threadIdx.x;
  if (i >= N * 96) return;
  int r = i / 96, k = i % 96;
  vb[i] = (k < 86) ? f2bf(v[(size_t)r * 86 + k]) : (unsigned short)0;
}

// ---------------- double-buffered LDS MFMA GEMM ----------------
// out = relu(A0@W0+A1@W1+A2@W2+b)*noise; 512 thr = 8 waves (2M x 4O);
// tile BM x 128; K-step KS; one barrier per step; issue-early/write-late prefetch.
template <int BM, int FPAD, int KS>
__global__ __launch_bounds__(512, 4) void gemm3_db(
    const unsigned short* __restrict__ A0, const unsigned short* __restrict__ A1,
    const unsigned short* __restrict__ A2,
    const unsigned short* __restrict__ Wt, const float* __restrict__ bias,
    int M, int O, float* __restrict__ out, unsigned short* __restrict__ outb,
    int obstride, int fold) {
  constexpr int BN = 128;
  constexpr int NSP = FPAD / KS;        // K-steps per operand
  constexpr int NSTEP = 3 * NSP;
  constexpr int CPR = KS / 8;           // u16x8 chunks per row
  constexpr int LST = KS + 8;           // LDS row stride (u16): +16B pad
  constexpr int NA = BM * CPR;
  constexpr int NB = BN * CPR;
  constexpr int ACH = (NA + 511) / 512;
  constexpr int BCH = (NB + 511) / 512;
  constexpr int MFR = BM / 32;
  constexpr int KK = KS / 32;

  __shared__ unsigned short sA[2][BM * LST];
  __shared__ unsigned short sB[2][BN * LST];

  const int tid = threadIdx.x;
  const int lane = tid & 63;
  const int wave = tid >> 6;
  const int wm = wave >> 2, wo = wave & 3;
  const int bm = blockIdx.x * BM;
  const int bo = blockIdx.y * BN;
  const int l15 = lane & 15;
  const int kg = (lane >> 4) * 8;

  f32x4 acc[MFR][2] = {};
  const unsigned short* As[3] = {A0, A1, A2};

  u16x8 ra[ACH], rb[BCH];

  auto issue = [&](int s) {
    int p = s / NSP, k0 = (s % NSP) * KS;
    const unsigned short* __restrict__ A = As[p];
    const unsigned short* __restrict__ B = Wt + (size_t)p * O * FPAD;
#pragma unroll
    for (int c = 0; c < ACH; ++c) {
      int idx = tid + c * 512;
      if (NA % 512 == 0 || idx < NA) {
        int row = idx / CPR, ch = (idx % CPR) * 8;
        int gm = bm + row; if (gm >= M) gm = M - 1;   // clamp; stores guarded
        ra[c] = *(const u16x8*)(A + (size_t)gm * FPAD + k0 + ch);
      }
    }
#pragma unroll
    for (int c = 0; c < BCH; ++c) {
      int idx = tid + c * 512;
      if (NB % 512 == 0 || idx < NB) {
        int row = idx / CPR, ch = (idx % CPR) * 8;
        rb[c] = *(const u16x8*)(B + (size_t)(bo + row) * FPAD + k0 + ch);
      }
    }
  };

  auto lds_write = [&](int buf) {
#pragma unroll
    for (int c = 0; c < ACH; ++c) {
      int idx = tid + c * 512;
      if (NA % 512 == 0 || idx < NA) {
        int row = idx / CPR, ch = (idx % CPR) * 8;
        *(u16x8*)&sA[buf][row * LST + ch] = ra[c];
      }
    }
#pragma unroll
    for (int c = 0; c < BCH; ++c) {
      int idx = tid + c * 512;
      if (NB % 512 == 0 || idx < NB) {
        int row = idx / CPR, ch = (idx % CPR) * 8;
        *(u16x8*)&sB[buf][row * LST + ch] = rb[c];
      }
    }
  };

  auto compute = [&](int buf) {
#pragma unroll
    for (int kk = 0; kk < KK; ++kk) {
      bf16x8 af[MFR], bfr[2];
#pragma unroll
      for (int mi = 0; mi < MFR; ++mi)
        af[mi] = *(const bf16x8*)&sA[buf][(wm * (BM / 2) + mi * 16 + l15) * LST + kk * 32 + kg];
#pragma unroll
      for (int ni = 0; ni < 2; ++ni)
        bfr[ni] = *(const bf16x8*)&sB[buf][(wo * 32 + ni * 16 + l15) * LST + kk * 32 + kg];
#pragma unroll
      for (int mi = 0; mi < MFR; ++mi)
#pragma unroll
        for (int ni = 0; ni < 2; ++ni)
          acc[mi][ni] = __builtin_amdgcn_mfma_f32_16x16x32_bf16(af[mi], bfr[ni], acc[mi][ni], 0, 0, 0);
    }
  };

  // prologue: stage step 0 into buf 0
  issue(0);
  lds_write(0);
  __syncthreads();

  int cur = 0;
#pragma unroll
  for (int s = 0; s < NSTEP; ++s) {
    if (s + 1 < NSTEP) issue(s + 1);      // loads in flight during compute
    compute(cur);
    if (s + 1 < NSTEP) {
      lds_write(cur ^ 1);                 // vmcnt-wait lands after compute
      __syncthreads();
      cur ^= 1;
    }
  }

  // epilogue: bias + relu + threefry noise (+ bf16 shadow for next layer)
  uint32_t f0 = 0u, f1 = (uint32_t)fold;
  threefry2x32(0u, 42u, f0, f1);
  const int r0 = (lane >> 4) * 4;
#pragma unroll
  for (int mi = 0; mi < MFR; ++mi) {
#pragma unroll
    for (int r = 0; r < 4; ++r) {
      int gm = bm + wm * (BM / 2) + mi * 16 + r0 + r;
      if (gm >= M) continue;
#pragma unroll
      for (int ni = 0; ni < 2; ++ni) {
        int go = bo + wo * 32 + ni * 16 + l15;
        float vv = acc[mi][ni][r] + bias[go];
        vv = vv > 0.0f ? vv : 0.0f;
        uint32_t a = 0u, b = (uint32_t)(gm * O + go);
        threefry2x32(f0, f1, a, b);
        float res = vv * normal_from_bits(a ^ b);
        out[(size_t)gm * O + go] = res;
        if (outb) outb[(size_t)gm * obstride + go] = f2bf(res);
      }
    }
  }
}

// ---------------- host orchestration ----------------
extern "C" void kernel_launch(void* const* d_in, const int* in_sizes, int n_in,
                              void* d_out, int out_size, void* d_ws, size_t ws_size,
                              hipStream_t stream) {
  const float* v    = (const float*)d_in[0];
  const int*  edges = (const int*)d_in[1];
  const float* W1 = (const float*)d_in[2];
  const float* b1 = (const float*)d_in[3];
  const float* W2 = (const float*)d_in[4];
  const float* b2 = (const float*)d_in[5];
  const float* W3 = (const float*)d_in[6];
  const float* b3 = (const float*)d_in[7];
  float* out = (float*)d_out;

  const int N = in_sizes[0] / 86;
  const int E = in_sizes[1] / 2;
  const int* rows = edges;
  const int* cols = edges + E;

  // ---- ws carve (16B-aligned chunks) ----
  uintptr_t cur = (uintptr_t)d_ws;
  auto alloc = [&](size_t bytes) {
    cur = (cur + 15) & ~(uintptr_t)15;
    void* p = (void*)cur;
    cur += bytes;
    return p;
  };
  float2* ecv          = (float2*)alloc((size_t)E * 8);
  int* counts          = (int*)alloc((size_t)N * 4);
  int* degs            = (int*)alloc((size_t)N * 4);
  int* row_ptr         = (int*)alloc((size_t)(N + 1) * 4);
  int* cursor          = (int*)alloc((size_t)N * 4);
  float* dinv          = (float*)alloc((size_t)N * 4);
  unsigned short* tx1b = (unsigned short*)alloc((size_t)N * 256 * 2);
  unsigned short* tx2b = (unsigned short*)alloc((size_t)N * 256 * 2);
  unsigned short* vb   = (unsigned short*)alloc((size_t)N * 96 * 2);
  unsigned short* x1b  = (unsigned short*)alloc((size_t)N * 128 * 2);
  unsigned short* x2b  = (unsigned short*)alloc((size_t)N * 256 * 2);
  unsigned short* Wt   = (unsigned short*)alloc((size_t)3 * 512 * 256 * 2);

  float* x1 = out;
  float* x2 = x1 + (size_t)N * 128;
  float* x3 = x2 + (size_t)N * 256;

  // CSR build + norm
  hipMemsetAsync(counts, 0, (size_t)2 * N * sizeof(int), stream);
  count_kernel<<<(E + 255) / 256, 256, 0, stream>>>(rows, cols, counts, degs, E);
  dinv_kernel<<<(N + 255) / 256, 256, 0, stream>>>(degs, dinv, N);
  scan_kernel<<<1, SCAN_T, 0, stream>>>(counts, row_ptr, cursor, N);
  fill_kernel<<<(E + 255) / 256, 256, 0, stream>>>(rows, cols, dinv, cursor, ecv, E);
  vconv_kernel<<<(N * 96 + 255) / 256, 256, 0, stream>>>(v, vb, N);

  const int pblocks = (N + 3) / 4;

  // ---- layer 1: F=86 (pad 96), O=128; BM=64, KS=32 ----
  {
    wtrans_kernel<<<(3 * 128 * 96 + 255) / 256, 256, 0, stream>>>(W1, Wt, 86, 96, 128);
    gather_prop<2, 0><<<pblocks, 256, 0, stream>>>(row_ptr, ecv, vb, 96, nullptr, 0, tx1b, N, 86, 96);
    gather_prop<2, 1><<<pblocks, 256, 0, stream>>>(row_ptr, ecv, tx1b, 96, v, 86, tx2b, N, 86, 96);
    dim3 g((N + 63) / 64, 1);
    gemm3_db<64, 96, 32><<<g, 512, 0, stream>>>(vb, tx1b, tx2b, Wt, b1, N, 128, x1, x1b, 128, 1);
  }
  // ---- layer 2: F=128, O=256; BM=128, KS=64 ----
  {
    wtrans_kernel<<<(3 * 256 * 128 + 255) / 256, 256, 0, stream>>>(W2, Wt, 128, 128, 256);
    gather_prop<2, 0><<<pblocks, 256, 0, stream>>>(row_ptr, ecv, x1b, 128, nullptr, 0, tx1b, N, 128, 128);
    gather_prop<2, 1><<<pblocks, 256, 0, stream>>>(row_ptr, ecv, tx1b, 128, x1, 128, tx2b, N, 128, 128);
    dim3 g((N + 127) / 128, 2);
    gemm3_db<128, 128, 64><<<g, 512, 0, stream>>>(x1b, tx1b, tx2b, Wt, b2, N, 256, x2, x2b, 256, 2);
  }
  // ---- layer 3: F=256, O=512; BM=128, KS=64 ----
  {
    wtrans_kernel<<<(3 * 512 * 256 + 255) / 256, 256, 0, stream>>>(W3, Wt, 256, 256, 512);
    gather_prop<4, 0><<<pblocks, 256, 0, stream>>>(row_ptr, ecv, x2b, 256, nullptr, 0, tx1b, N, 256, 256);
    gather_prop<4, 1><<<pblocks, 256, 0, stream>>>(row_ptr, ecv, tx1b, 256, x2, 256, tx2b, N, 256, 256);
    dim3 g((N + 127) / 128, 4);
    gemm3_db<128, 256, 64><<<g, 512, 0, stream>>>(x2b, tx1b, tx2b, Wt, b3, N, 512, x3, nullptr, 0, 3);
  }
}

// Round 9
// 405.200 us; speedup vs baseline: 1.0068x; 1.0068x over previous
//
#include <hip/hip_runtime.h>
#include <stdint.h>
#include <math.h>

#define DEV static __device__ __forceinline__

typedef __attribute__((ext_vector_type(8))) short bf16x8;
typedef __attribute__((ext_vector_type(4))) float f32x4;
typedef __attribute__((ext_vector_type(8))) unsigned short u16x8;

// ---------------- Threefry-2x32/20 (exact JAX schedule) ----------------
DEV uint32_t rotl32(uint32_t v, int d) { return (v << d) | (v >> (32 - d)); }

DEV void threefry2x32(uint32_t k0, uint32_t k1, uint32_t& x0, uint32_t& x1) {
  const uint32_t k2 = k0 ^ k1 ^ 0x1BD11BDAu;
  x0 += k0; x1 += k1;
#define TFR(R) { x0 += x1; x1 = rotl32(x1, R) ^ x0; }
  TFR(13) TFR(15) TFR(26) TFR(6)
  x0 += k1; x1 += k2 + 1u;
  TFR(17) TFR(29) TFR(16) TFR(24)
  x0 += k2; x1 += k0 + 2u;
  TFR(13) TFR(15) TFR(26) TFR(6)
  x0 += k0; x1 += k1 + 3u;
  TFR(17) TFR(29) TFR(16) TFR(24)
  x0 += k1; x1 += k2 + 4u;
  TFR(13) TFR(15) TFR(26) TFR(6)
  x0 += k2; x1 += k0 + 5u;
#undef TFR
}

// ---------------- erfinv (XLA f32 ErfInv, Giles 2012) ----------------
DEV float erfinv_f32(float x) {
  float w = -log1pf(-x * x);
  float p;
  if (w < 5.0f) {
    w -= 2.5f;
    p = 2.81022636e-08f;
    p = fmaf(p, w, 3.43273939e-07f);
    p = fmaf(p, w, -3.5233877e-06f);
    p = fmaf(p, w, -4.39150654e-06f);
    p = fmaf(p, w, 0.00021858087f);
    p = fmaf(p, w, -0.00125372503f);
    p = fmaf(p, w, -0.00417768164f);
    p = fmaf(p, w, 0.246640727f);
    p = fmaf(p, w, 1.50140941f);
  } else {
    w = sqrtf(w) - 3.0f;
    p = -0.000200214257f;
    p = fmaf(p, w, 0.000100950558f);
    p = fmaf(p, w, 0.00134934322f);
    p = fmaf(p, w, -0.00367342844f);
    p = fmaf(p, w, 0.00573950773f);
    p = fmaf(p, w, -0.0076224613f);
    p = fmaf(p, w, 0.00943887047f);
    p = fmaf(p, w, 1.00167406f);
    p = fmaf(p, w, 2.83297682f);
  }
  return p * x;
}

DEV float normal_from_bits(uint32_t bits) {
  float f = __uint_as_float((bits >> 9) | 0x3F800000u) - 1.0f;
  const float lo = -0.99999994f;            // nextafter(-1, 0) in f32
  float u = fmaf(f, 2.0f, lo);
  u = fmaxf(u, lo);
  return 1.41421356f * erfinv_f32(u);
}

DEV unsigned short f2bf(float f) {   // RTNE f32 -> bf16
  uint32_t u = __float_as_uint(f);
  uint32_t r = u + 0x7FFFu + ((u >> 16) & 1u);
  return (unsigned short)(r >> 16);
}

DEV float bf2f(uint32_t h) { return __uint_as_float(h << 16); }

// ---------------- CSR build ----------------
__global__ void count_kernel(const int* __restrict__ rows, const int* __restrict__ cols,
                             int* __restrict__ counts, int* __restrict__ degs, int E) {
  int e = blockIdx.x * blockDim.x + threadIdx.x;
  if (e < E) {
    int r = rows[e];
    atomicAdd(&counts[r], 1);
    if (r != cols[e]) atomicAdd(&degs[r], 1);
  }
}

#define SCAN_T 1024
__global__ __launch_bounds__(SCAN_T) void scan_kernel(const int* __restrict__ counts,
                                                      int* __restrict__ row_ptr,
                                                      int* __restrict__ cursor, int N) {
  __shared__ int sa[SCAN_T], sb[SCAN_T];
  const int t = threadIdx.x;
  const int CH = (N + SCAN_T - 1) / SCAN_T;
  int base = t * CH;
  int psum = 0;
  for (int k = 0; k < CH; ++k) {
    int idx = base + k;
    if (idx < N) psum += counts[idx];
  }
  sa[t] = psum;
  __syncthreads();
  int* src = sa; int* dst = sb;
  for (int off = 1; off < SCAN_T; off <<= 1) {
    int v = src[t];
    if (t >= off) v += src[t - off];
    dst[t] = v;
    __syncthreads();
    int* tmp = src; src = dst; dst = tmp;
  }
  int running = src[t] - psum;
  for (int k = 0; k < CH; ++k) {
    int idx = base + k;
    if (idx < N) {
      row_ptr[idx] = running;
      cursor[idx] = running;
      running += counts[idx];
    }
  }
  if (t == SCAN_T - 1) row_ptr[N] = running;
}

__global__ void fill_kernel(const int* __restrict__ rows, const int* __restrict__ cols,
                            const int* __restrict__ degs, int* __restrict__ cursor,
                            float2* __restrict__ ecv, int E) {
  int e = blockIdx.x * blockDim.x + threadIdx.x;
  if (e < E) {
    int r = rows[e], c = cols[e];
    int dr = degs[r], dc = degs[c];
    float w = (r != c && dr > 0 && dc > 0) ? -rsqrtf((float)dr) * rsqrtf((float)dc) : 0.0f;
    int pos = atomicAdd(&cursor[r], 1);
    ecv[pos] = make_float2(__int_as_float(c), w);
  }
}

// ---------------- row loader: VEC floats from bf16 source ----------------
template <int VEC>
DEV void ldrow(const unsigned short* base, size_t off, float* v) {
  const unsigned short* p = base + off;
  if (VEC == 4) {
    uint2 u = *(const uint2*)p;
    v[0] = bf2f(u.x & 0xffffu); v[1] = bf2f(u.x >> 16);
    v[2] = bf2f(u.y & 0xffffu); v[3] = bf2f(u.y >> 16);
  } else {
    uint32_t u = *(const uint32_t*)p;
    v[0] = bf2f(u & 0xffffu); v[1] = bf2f(u >> 16);
  }
}

// ---------------- propagation: one wave per node, deep-unrolled gather ----------------
// SUB=0: outb = bf16(P x);  SUB=1: outb = bf16(2*P x - xsub)
template <int VEC, int SUB, int U>
__global__ __launch_bounds__(256) void gather_prop(
    const int* __restrict__ row_ptr, const float2* __restrict__ ecv,
    const unsigned short* __restrict__ xsrc, int sstride,
    const float* __restrict__ xsub, int substride,
    unsigned short* __restrict__ outb, int N, int F, int Fpad) {
  const int wave = threadIdx.x >> 6, lane = threadIdx.x & 63;
  const int node = blockIdx.x * 4 + wave;
  if (node >= N) return;
  const int f0 = lane * VEC;
  if (f0 >= Fpad) return;
  const bool live = (f0 + VEC) <= F;
  float acc[VEC] = {};
  if (live) {
    const int s = row_ptr[node], e = row_ptr[node + 1];
    int j = s;
    for (; j + U <= e; j += U) {
      float2 cw[U];
      float vv[U][VEC];
#pragma unroll
      for (int q = 0; q < U; ++q) cw[q] = ecv[j + q];
#pragma unroll
      for (int q = 0; q < U; ++q)
        ldrow<VEC>(xsrc, (size_t)__float_as_int(cw[q].x) * sstride + f0, vv[q]);
#pragma unroll
      for (int q = 0; q < U; ++q)
#pragma unroll
        for (int z = 0; z < VEC; ++z) acc[z] = fmaf(cw[q].y, vv[q][z], acc[z]);
    }
    for (; j + 4 <= e; j += 4) {
      float2 cw[4];
      float vv[4][VEC];
#pragma unroll
      for (int q = 0; q < 4; ++q) cw[q] = ecv[j + q];
#pragma unroll
      for (int q = 0; q < 4; ++q)
        ldrow<VEC>(xsrc, (size_t)__float_as_int(cw[q].x) * sstride + f0, vv[q]);
#pragma unroll
      for (int q = 0; q < 4; ++q)
#pragma unroll
        for (int z = 0; z < VEC; ++z) acc[z] = fmaf(cw[q].y, vv[q][z], acc[z]);
    }
    for (; j < e; ++j) {
      float2 cw = ecv[j];
      float vv[VEC];
      ldrow<VEC>(xsrc, (size_t)__float_as_int(cw.x) * sstride + f0, vv);
#pragma unroll
      for (int z = 0; z < VEC; ++z) acc[z] = fmaf(cw.y, vv[z], acc[z]);
    }
    if (SUB) {
      const float* sb = xsub + (size_t)node * substride + f0;
#pragma unroll
      for (int z = 0; z < VEC; ++z) acc[z] = fmaf(2.0f, acc[z], -sb[z]);
    }
  }
  size_t ob = (size_t)node * Fpad + f0;
  if (VEC == 4) {
    uint2 u;
    u.x = (uint32_t)f2bf(acc[0]) | ((uint32_t)f2bf(acc[1]) << 16);
    u.y = (uint32_t)f2bf(acc[2]) | ((uint32_t)f2bf(acc[3]) << 16);
    *(uint2*)&outb[ob] = u;
  } else {
    uint32_t u = (uint32_t)f2bf(acc[0]) | ((uint32_t)f2bf(acc[1]) << 16);
    *(uint32_t*)&outb[ob] = u;
  }
}

// ---------------- weight transpose+convert: Wt[p][o][k] = bf16(W[p][k][o]) ----------------
__global__ void wtrans_kernel(const float* __restrict__ W, unsigned short* __restrict__ Wt,
                              int F, int Fpad, int O) {
  int idx = blockIdx.x * 256 + threadIdx.x;
  int total = 3 * O * Fpad;
  if (idx >= total) return;
  int k = idx % Fpad;
  int o = (idx / Fpad) % O;
  int p = idx / (Fpad * O);
  Wt[idx] = (k < F) ? f2bf(W[((size_t)p * F + k) * O + o]) : (unsigned short)0;
}

// ---------------- input convert: vb[i][k<96] = bf16(v[i][k<86]) ----------------
__global__ void vconv_kernel(const float* __restrict__ v, unsigned short* __restrict__ vb, int N) {
  int i = blockIdx.x * 256 + threadIdx.x;
  if (i >= N * 96) return;
  int r = i / 96, k = i % 96;
  vb[i] = (k < 86) ? f2bf(v[(size_t)r * 86 + k]) : (unsigned short)0;
}

// ---------------- standalone noise: nb[i] = N(0,1) from threefry(fold_in(key42,FOLD), i) ----------------
template <int FOLD>
__global__ __launch_bounds__(256) void noise_kernel(float* __restrict__ nb, int total4) {
  // fold_in(key=(0,42), FOLD): constant-folded
  uint32_t f0 = 0u, f1 = (uint32_t)FOLD;
  threefry2x32(0u, 42u, f0, f1);
  int i4 = blockIdx.x * 256 + threadIdx.x;
  if (i4 >= total4) return;
  uint32_t base = (uint32_t)i4 * 4u;
  float4 r;
  {
    uint32_t a = 0u, b = base + 0u; threefry2x32(f0, f1, a, b); r.x = normal_from_bits(a ^ b);
  }
  {
    uint32_t a = 0u, b = base + 1u; threefry2x32(f0, f1, a, b); r.y = normal_from_bits(a ^ b);
  }
  {
    uint32_t a = 0u, b = base + 2u; threefry2x32(f0, f1, a, b); r.z = normal_from_bits(a ^ b);
  }
  {
    uint32_t a = 0u, b = base + 3u; threefry2x32(f0, f1, a, b); r.w = normal_from_bits(a ^ b);
  }
  *(float4*)&nb[(size_t)base] = r;
}

// ---------------- double-buffered LDS MFMA GEMM ----------------
// out = relu(A0@W0+A1@W1+A2@W2+b)*noise; 512 thr = 8 waves (2M x 4O);
// tile BM x 128; K-step KS; one barrier per step; issue-early/write-late prefetch.
template <int BM, int FPAD, int KS>
__global__ __launch_bounds__(512, 4) void gemm3_db(
    const unsigned short* __restrict__ A0, const unsigned short* __restrict__ A1,
    const unsigned short* __restrict__ A2,
    const unsigned short* __restrict__ Wt, const float* __restrict__ bias,
    const float* __restrict__ noise,
    int M, int O, float* __restrict__ out, unsigned short* __restrict__ outb,
    int obstride) {
  constexpr int BN = 128;
  constexpr int NSP = FPAD / KS;
  constexpr int NSTEP = 3 * NSP;
  constexpr int CPR = KS / 8;
  constexpr int LST = KS + 8;
  constexpr int NA = BM * CPR;
  constexpr int NB = BN * CPR;
  constexpr int ACH = (NA + 511) / 512;
  constexpr int BCH = (NB + 511) / 512;
  constexpr int MFR = BM / 32;
  constexpr int KK = KS / 32;

  __shared__ unsigned short sA[2][BM * LST];
  __shared__ unsigned short sB[2][BN * LST];

  const int tid = threadIdx.x;
  const int lane = tid & 63;
  const int wave = tid >> 6;
  const int wm = wave >> 2, wo = wave & 3;
  const int bm = blockIdx.x * BM;
  const int bo = blockIdx.y * BN;
  const int l15 = lane & 15;
  const int kg = (lane >> 4) * 8;

  f32x4 acc[MFR][2] = {};
  const unsigned short* As[3] = {A0, A1, A2};

  u16x8 ra[ACH], rb[BCH];

  auto issue = [&](int s) {
    int p = s / NSP, k0 = (s % NSP) * KS;
    const unsigned short* __restrict__ A = As[p];
    const unsigned short* __restrict__ B = Wt + (size_t)p * O * FPAD;
#pragma unroll
    for (int c = 0; c < ACH; ++c) {
      int idx = tid + c * 512;
      if (NA % 512 == 0 || idx < NA) {
        int row = idx / CPR, ch = (idx % CPR) * 8;
        int gm = bm + row; if (gm >= M) gm = M - 1;   // clamp; stores guarded
        ra[c] = *(const u16x8*)(A + (size_t)gm * FPAD + k0 + ch);
      }
    }
#pragma unroll
    for (int c = 0; c < BCH; ++c) {
      int idx = tid + c * 512;
      if (NB % 512 == 0 || idx < NB) {
        int row = idx / CPR, ch = (idx % CPR) * 8;
        rb[c] = *(const u16x8*)(B + (size_t)(bo + row) * FPAD + k0 + ch);
      }
    }
  };

  auto lds_write = [&](int buf) {
#pragma unroll
    for (int c = 0; c < ACH; ++c) {
      int idx = tid + c * 512;
      if (NA % 512 == 0 || idx < NA) {
        int row = idx / CPR, ch = (idx % CPR) * 8;
        *(u16x8*)&sA[buf][row * LST + ch] = ra[c];
      }
    }
#pragma unroll
    for (int c = 0; c < BCH; ++c) {
      int idx = tid + c * 512;
      if (NB % 512 == 0 || idx < NB) {
        int row = idx / CPR, ch = (idx % CPR) * 8;
        *(u16x8*)&sB[buf][row * LST + ch] = rb[c];
      }
    }
  };

  auto compute = [&](int buf) {
#pragma unroll
    for (int kk = 0; kk < KK; ++kk) {
      bf16x8 af[MFR], bfr[2];
#pragma unroll
      for (int mi = 0; mi < MFR; ++mi)
        af[mi] = *(const bf16x8*)&sA[buf][(wm * (BM / 2) + mi * 16 + l15) * LST + kk * 32 + kg];
#pragma unroll
      for (int ni = 0; ni < 2; ++ni)
        bfr[ni] = *(const bf16x8*)&sB[buf][(wo * 32 + ni * 16 + l15) * LST + kk * 32 + kg];
#pragma unroll
      for (int mi = 0; mi < MFR; ++mi)
#pragma unroll
        for (int ni = 0; ni < 2; ++ni)
          acc[mi][ni] = __builtin_amdgcn_mfma_f32_16x16x32_bf16(af[mi], bfr[ni], acc[mi][ni], 0, 0, 0);
    }
  };

  issue(0);
  lds_write(0);
  __syncthreads();

  int cur = 0;
#pragma unroll
  for (int s = 0; s < NSTEP; ++s) {
    if (s + 1 < NSTEP) issue(s + 1);
    compute(cur);
    if (s + 1 < NSTEP) {
      lds_write(cur ^ 1);
      __syncthreads();
      cur ^= 1;
    }
  }

  // epilogue: bias + relu + precomputed-noise multiply (+ bf16 shadow)
  const int r0 = (lane >> 4) * 4;
#pragma unroll
  for (int mi = 0; mi < MFR; ++mi) {
#pragma unroll
    for (int r = 0; r < 4; ++r) {
      int gm = bm + wm * (BM / 2) + mi * 16 + r0 + r;
      if (gm >= M) continue;
#pragma unroll
      for (int ni = 0; ni < 2; ++ni) {
        int go = bo + wo * 32 + ni * 16 + l15;
        float vv = acc[mi][ni][r] + bias[go];
        vv = vv > 0.0f ? vv : 0.0f;
        float res = vv * noise[(size_t)gm * O + go];
        out[(size_t)gm * O + go] = res;
        if (outb) outb[(size_t)gm * obstride + go] = f2bf(res);
      }
    }
  }
}

// ---------------- host orchestration ----------------
extern "C" void kernel_launch(void* const* d_in, const int* in_sizes, int n_in,
                              void* d_out, int out_size, void* d_ws, size_t ws_size,
                              hipStream_t stream) {
  const float* v    = (const float*)d_in[0];
  const int*  edges = (const int*)d_in[1];
  const float* W1 = (const float*)d_in[2];
  const float* b1 = (const float*)d_in[3];
  const float* W2 = (const float*)d_in[4];
  const float* b2 = (const float*)d_in[5];
  const float* W3 = (const float*)d_in[6];
  const float* b3 = (const float*)d_in[7];
  float* out = (float*)d_out;

  const int N = in_sizes[0] / 86;
  const int E = in_sizes[1] / 2;
  const int* rows = edges;
  const int* cols = edges + E;

  // ---- ws carve (16B-aligned chunks) ----
  uintptr_t cur = (uintptr_t)d_ws;
  auto alloc = [&](size_t bytes) {
    cur = (cur + 15) & ~(uintptr_t)15;
    void* p = (void*)cur;
    cur += bytes;
    return p;
  };
  float2* ecv          = (float2*)alloc((size_t)E * 8);
  int* counts          = (int*)alloc((size_t)N * 4);
  int* degs            = (int*)alloc((size_t)N * 4);
  int* row_ptr         = (int*)alloc((size_t)(N + 1) * 4);
  int* cursor          = (int*)alloc((size_t)N * 4);
  unsigned short* tx1b = (unsigned short*)alloc((size_t)N * 256 * 2);
  unsigned short* tx2b = (unsigned short*)alloc((size_t)N * 256 * 2);
  unsigned short* vb   = (unsigned short*)alloc((size_t)N * 96 * 2);
  unsigned short* x1b  = (unsigned short*)alloc((size_t)N * 128 * 2);
  unsigned short* x2b  = (unsigned short*)alloc((size_t)N * 256 * 2);
  unsigned short* Wt   = (unsigned short*)alloc((size_t)3 * 512 * 256 * 2);
  float* nbuf          = (float*)alloc((size_t)N * 512 * 4);   // reused per layer

  float* x1 = out;
  float* x2 = x1 + (size_t)N * 128;
  float* x3 = x2 + (size_t)N * 256;

  // CSR build + norm
  hipMemsetAsync(counts, 0, (size_t)2 * N * sizeof(int), stream);
  count_kernel<<<(E + 255) / 256, 256, 0, stream>>>(rows, cols, counts, degs, E);
  scan_kernel<<<1, SCAN_T, 0, stream>>>(counts, row_ptr, cursor, N);
  fill_kernel<<<(E + 255) / 256, 256, 0, stream>>>(rows, cols, degs, cursor, ecv, E);
  vconv_kernel<<<(N * 96 + 255) / 256, 256, 0, stream>>>(v, vb, N);

  const int pblocks = (N + 3) / 4;

  // ---- layer 1: F=86 (pad 96), O=128; BM=64, KS=32 ----
  {
    wtrans_kernel<<<(3 * 128 * 96 + 255) / 256, 256, 0, stream>>>(W1, Wt, 86, 96, 128);
    gather_prop<2, 0, 16><<<pblocks, 256, 0, stream>>>(row_ptr, ecv, vb, 96, nullptr, 0, tx1b, N, 86, 96);
    gather_prop<2, 1, 16><<<pblocks, 256, 0, stream>>>(row_ptr, ecv, tx1b, 96, v, 86, tx2b, N, 86, 96);
    int t4 = N * 128 / 4;
    noise_kernel<1><<<(t4 + 255) / 256, 256, 0, stream>>>(nbuf, t4);
    dim3 g((N + 63) / 64, 1);
    gemm3_db<64, 96, 32><<<g, 512, 0, stream>>>(vb, tx1b, tx2b, Wt, b1, nbuf, N, 128, x1, x1b, 128);
  }
  // ---- layer 2: F=128, O=256; BM=128, KS=64 ----
  {
    wtrans_kernel<<<(3 * 256 * 128 + 255) / 256, 256, 0, stream>>>(W2, Wt, 128, 128, 256);
    gather_prop<2, 0, 16><<<pblocks, 256, 0, stream>>>(row_ptr, ecv, x1b, 128, nullptr, 0, tx1b, N, 128, 128);
    gather_prop<2, 1, 16><<<pblocks, 256, 0, stream>>>(row_ptr, ecv, tx1b, 128, x1, 128, tx2b, N, 128, 128);
    int t4 = N * 256 / 4;
    noise_kernel<2><<<(t4 + 255) / 256, 256, 0, stream>>>(nbuf, t4);
    dim3 g((N + 127) / 128, 2);
    gemm3_db<128, 128, 64><<<g, 512, 0, stream>>>(x1b, tx1b, tx2b, Wt, b2, nbuf, N, 256, x2, x2b, 256);
  }
  // ---- layer 3: F=256, O=512; BM=128, KS=64 ----
  {
    wtrans_kernel<<<(3 * 512 * 256 + 255) / 256, 256, 0, stream>>>(W3, Wt, 256, 256, 512);
    gather_prop<4, 0, 12><<<pblocks, 256, 0, stream>>>(row_ptr, ecv, x2b, 256, nullptr, 0, tx1b, N, 256, 256);
    gather_prop<4, 1, 12><<<pblocks, 256, 0, stream>>>(row_ptr, ecv, tx1b, 256, x2, 256, tx2b, N, 256, 256);
    int t4 = N * 512 / 4;
    noise_kernel<3><<<(t4 + 255) / 256, 256, 0, stream>>>(nbuf, t4);
    dim3 g((N + 127) / 128, 4);
    gemm3_db<128, 256, 64><<<g, 512, 0, stream>>>(x2b, tx1b, tx2b, Wt, b3, nbuf, N, 512, x3, nullptr, 0);
  }
}

// Round 10
// 370.319 us; speedup vs baseline: 1.1016x; 1.0942x over previous
//
#include <hip/hip_runtime.h>
#include <stdint.h>
#include <math.h>

#define DEV static __device__ __forceinline__

typedef __attribute__((ext_vector_type(8))) short bf16x8;
typedef __attribute__((ext_vector_type(4))) float f32x4;
typedef __attribute__((ext_vector_type(8))) unsigned short u16x8;

// ---------------- Threefry-2x32/20 (exact JAX schedule) ----------------
DEV uint32_t rotl32(uint32_t v, int d) { return (v << d) | (v >> (32 - d)); }

DEV void threefry2x32(uint32_t k0, uint32_t k1, uint32_t& x0, uint32_t& x1) {
  const uint32_t k2 = k0 ^ k1 ^ 0x1BD11BDAu;
  x0 += k0; x1 += k1;
#define TFR(R) { x0 += x1; x1 = rotl32(x1, R) ^ x0; }
  TFR(13) TFR(15) TFR(26) TFR(6)
  x0 += k1; x1 += k2 + 1u;
  TFR(17) TFR(29) TFR(16) TFR(24)
  x0 += k2; x1 += k0 + 2u;
  TFR(13) TFR(15) TFR(26) TFR(6)
  x0 += k0; x1 += k1 + 3u;
  TFR(17) TFR(29) TFR(16) TFR(24)
  x0 += k1; x1 += k2 + 4u;
  TFR(13) TFR(15) TFR(26) TFR(6)
  x0 += k2; x1 += k0 + 5u;
#undef TFR
}

// ---------------- erfinv (XLA f32 ErfInv, Giles 2012) ----------------
DEV float erfinv_f32(float x) {
  float w = -log1pf(-x * x);
  float p;
  if (w < 5.0f) {
    w -= 2.5f;
    p = 2.81022636e-08f;
    p = fmaf(p, w, 3.43273939e-07f);
    p = fmaf(p, w, -3.5233877e-06f);
    p = fmaf(p, w, -4.39150654e-06f);
    p = fmaf(p, w, 0.00021858087f);
    p = fmaf(p, w, -0.00125372503f);
    p = fmaf(p, w, -0.00417768164f);
    p = fmaf(p, w, 0.246640727f);
    p = fmaf(p, w, 1.50140941f);
  } else {
    w = sqrtf(w) - 3.0f;
    p = -0.000200214257f;
    p = fmaf(p, w, 0.000100950558f);
    p = fmaf(p, w, 0.00134934322f);
    p = fmaf(p, w, -0.00367342844f);
    p = fmaf(p, w, 0.00573950773f);
    p = fmaf(p, w, -0.0076224613f);
    p = fmaf(p, w, 0.00943887047f);
    p = fmaf(p, w, 1.00167406f);
    p = fmaf(p, w, 2.83297682f);
  }
  return p * x;
}

DEV float normal_from_bits(uint32_t bits) {
  float f = __uint_as_float((bits >> 9) | 0x3F800000u) - 1.0f;
  const float lo = -0.99999994f;            // nextafter(-1, 0) in f32
  float u = fmaf(f, 2.0f, lo);
  u = fmaxf(u, lo);
  return 1.41421356f * erfinv_f32(u);
}

DEV unsigned short f2bf(float f) {   // RTNE f32 -> bf16
  uint32_t u = __float_as_uint(f);
  uint32_t r = u + 0x7FFFu + ((u >> 16) & 1u);
  return (unsigned short)(r >> 16);
}

DEV float bf2f(uint32_t h) { return __uint_as_float(h << 16); }

// noise for flat index range [i4*4, i4*4+4) under folded key (f0,f1)
DEV float4 noise4(uint32_t f0, uint32_t f1, uint32_t i4) {
  uint32_t base = i4 * 4u;
  float4 r;
  { uint32_t a = 0u, b = base + 0u; threefry2x32(f0, f1, a, b); r.x = normal_from_bits(a ^ b); }
  { uint32_t a = 0u, b = base + 1u; threefry2x32(f0, f1, a, b); r.y = normal_from_bits(a ^ b); }
  { uint32_t a = 0u, b = base + 2u; threefry2x32(f0, f1, a, b); r.z = normal_from_bits(a ^ b); }
  { uint32_t a = 0u, b = base + 3u; threefry2x32(f0, f1, a, b); r.w = normal_from_bits(a ^ b); }
  return r;
}

// ---------------- CSR build ----------------
__global__ void count_kernel(const int* __restrict__ rows, const int* __restrict__ cols,
                             int* __restrict__ counts, int* __restrict__ degs, int E) {
  int e = blockIdx.x * blockDim.x + threadIdx.x;
  if (e < E) {
    int r = rows[e];
    atomicAdd(&counts[r], 1);
    if (r != cols[e]) atomicAdd(&degs[r], 1);
  }
}

#define SCAN_T 1024
__global__ __launch_bounds__(SCAN_T) void scan_kernel(const int* __restrict__ counts,
                                                      int* __restrict__ row_ptr,
                                                      int* __restrict__ cursor, int N) {
  __shared__ int sa[SCAN_T], sb[SCAN_T];
  const int t = threadIdx.x;
  const int CH = (N + SCAN_T - 1) / SCAN_T;
  int base = t * CH;
  int psum = 0;
  for (int k = 0; k < CH; ++k) {
    int idx = base + k;
    if (idx < N) psum += counts[idx];
  }
  sa[t] = psum;
  __syncthreads();
  int* src = sa; int* dst = sb;
  for (int off = 1; off < SCAN_T; off <<= 1) {
    int v = src[t];
    if (t >= off) v += src[t - off];
    dst[t] = v;
    __syncthreads();
    int* tmp = src; src = dst; dst = tmp;
  }
  int running = src[t] - psum;
  for (int k = 0; k < CH; ++k) {
    int idx = base + k;
    if (idx < N) {
      row_ptr[idx] = running;
      cursor[idx] = running;
      running += counts[idx];
    }
  }
  if (t == SCAN_T - 1) row_ptr[N] = running;
}

__global__ void fill_kernel(const int* __restrict__ rows, const int* __restrict__ cols,
                            const int* __restrict__ degs, int* __restrict__ cursor,
                            float2* __restrict__ ecv, int E) {
  int e = blockIdx.x * blockDim.x + threadIdx.x;
  if (e < E) {
    int r = rows[e], c = cols[e];
    int dr = degs[r], dc = degs[c];
    float w = (r != c && dr > 0 && dc > 0) ? -rsqrtf((float)dr) * rsqrtf((float)dc) : 0.0f;
    int pos = atomicAdd(&cursor[r], 1);
    ecv[pos] = make_float2(__int_as_float(c), w);
  }
}

// ---------------- row loader: VEC floats from bf16 source ----------------
template <int VEC>
DEV void ldrow(const unsigned short* base, size_t off, float* v) {
  const unsigned short* p = base + off;
  if (VEC == 4) {
    uint2 u = *(const uint2*)p;
    v[0] = bf2f(u.x & 0xffffu); v[1] = bf2f(u.x >> 16);
    v[2] = bf2f(u.y & 0xffffu); v[3] = bf2f(u.y >> 16);
  } else {
    uint32_t u = *(const uint32_t*)p;
    v[0] = bf2f(u & 0xffffu); v[1] = bf2f(u >> 16);
  }
}

// ---------------- propagation + fused noise generation ----------------
// SUB=0: outb = bf16(P x);  SUB=1: outb = bf16(2*P x - xsub)
// Additionally fills nbuf float4-range [n4_begin, n4_end) with N(0,1) under fold FOLD
// (pure-VALU work that hides under gather latency via wave co-scheduling).
template <int VEC, int SUB, int FOLD>
__global__ __launch_bounds__(256) void gather_prop(
    const int* __restrict__ row_ptr, const float2* __restrict__ ecv,
    const unsigned short* __restrict__ xsrc, int sstride,
    const float* __restrict__ xsub, int substride,
    unsigned short* __restrict__ outb, int N, int F, int Fpad,
    float* __restrict__ nbuf, int n4_begin, int n4_end) {
  const int wave = threadIdx.x >> 6, lane = threadIdx.x & 63;
  const int node = blockIdx.x * 4 + wave;
  const int f0 = lane * VEC;
  if (node < N && f0 < Fpad) {
    const bool live = (f0 + VEC) <= F;
    float acc[VEC] = {};
    if (live) {
      const int s = row_ptr[node], e = row_ptr[node + 1];
      int j = s;
      for (; j + 8 <= e; j += 8) {
        float2 cw[8];
        float vv[8][VEC];
#pragma unroll
        for (int q = 0; q < 8; ++q) cw[q] = ecv[j + q];
#pragma unroll
        for (int q = 0; q < 8; ++q)
          ldrow<VEC>(xsrc, (size_t)__float_as_int(cw[q].x) * sstride + f0, vv[q]);
#pragma unroll
        for (int q = 0; q < 8; ++q)
#pragma unroll
          for (int z = 0; z < VEC; ++z) acc[z] = fmaf(cw[q].y, vv[q][z], acc[z]);
      }
      for (; j + 2 <= e; j += 2) {
        float2 cw[2];
        float vv[2][VEC];
#pragma unroll
        for (int q = 0; q < 2; ++q) cw[q] = ecv[j + q];
#pragma unroll
        for (int q = 0; q < 2; ++q)
          ldrow<VEC>(xsrc, (size_t)__float_as_int(cw[q].x) * sstride + f0, vv[q]);
#pragma unroll
        for (int q = 0; q < 2; ++q)
#pragma unroll
          for (int z = 0; z < VEC; ++z) acc[z] = fmaf(cw[q].y, vv[q][z], acc[z]);
      }
      for (; j < e; ++j) {
        float2 cw = ecv[j];
        float vv[VEC];
        ldrow<VEC>(xsrc, (size_t)__float_as_int(cw.x) * sstride + f0, vv);
#pragma unroll
        for (int z = 0; z < VEC; ++z) acc[z] = fmaf(cw.y, vv[z], acc[z]);
      }
      if (SUB) {
        const float* sb = xsub + (size_t)node * substride + f0;
#pragma unroll
        for (int z = 0; z < VEC; ++z) acc[z] = fmaf(2.0f, acc[z], -sb[z]);
      }
    }
    size_t ob = (size_t)node * Fpad + f0;
    if (VEC == 4) {
      uint2 u;
      u.x = (uint32_t)f2bf(acc[0]) | ((uint32_t)f2bf(acc[1]) << 16);
      u.y = (uint32_t)f2bf(acc[2]) | ((uint32_t)f2bf(acc[3]) << 16);
      *(uint2*)&outb[ob] = u;
    } else {
      uint32_t u = (uint32_t)f2bf(acc[0]) | ((uint32_t)f2bf(acc[1]) << 16);
      *(uint32_t*)&outb[ob] = u;
    }
  }
  // fused noise: grid-stride over assigned float4 range
  uint32_t f0k = 0u, f1k = (uint32_t)FOLD;
  threefry2x32(0u, 42u, f0k, f1k);
  const int gstride = gridDim.x * 256;
  for (int i4 = n4_begin + blockIdx.x * 256 + threadIdx.x; i4 < n4_end; i4 += gstride) {
    float4 r = noise4(f0k, f1k, (uint32_t)i4);
    *(float4*)&nbuf[(size_t)i4 * 4] = r;
  }
}

// ---------------- weight transpose+convert: Wt[p][o][k] = bf16(W[p][k][o]) ----------------
__global__ void wtrans_kernel(const float* __restrict__ W, unsigned short* __restrict__ Wt,
                              int F, int Fpad, int O) {
  int idx = blockIdx.x * 256 + threadIdx.x;
  int total = 3 * O * Fpad;
  if (idx >= total) return;
  int k = idx % Fpad;
  int o = (idx / Fpad) % O;
  int p = idx / (Fpad * O);
  Wt[idx] = (k < F) ? f2bf(W[((size_t)p * F + k) * O + o]) : (unsigned short)0;
}

// ---------------- input convert: vb[i][k<96] = bf16(v[i][k<86]) ----------------
__global__ void vconv_kernel(const float* __restrict__ v, unsigned short* __restrict__ vb, int N) {
  int i = blockIdx.x * 256 + threadIdx.x;
  if (i >= N * 96) return;
  int r = i / 96, k = i % 96;
  vb[i] = (k < 86) ? f2bf(v[(size_t)r * 86 + k]) : (unsigned short)0;
}

// ---------------- double-buffered LDS MFMA GEMM, 2-step-deep prefetch ----------------
// out = relu(A0@W0+A1@W1+A2@W2+b)*noise; 512 thr = 8 waves (2M x 4O);
// tile BM x 128; K-step KS; one barrier per step; two in-flight load sets.
template <int BM, int FPAD, int KS>
__global__ __launch_bounds__(512, 4) void gemm3_db(
    const unsigned short* __restrict__ A0, const unsigned short* __restrict__ A1,
    const unsigned short* __restrict__ A2,
    const unsigned short* __restrict__ Wt, const float* __restrict__ bias,
    const float* __restrict__ noise,
    int M, int O, float* __restrict__ out, unsigned short* __restrict__ outb,
    int obstride) {
  constexpr int BN = 128;
  constexpr int NSP = FPAD / KS;
  constexpr int NSTEP = 3 * NSP;
  constexpr int CPR = KS / 8;
  constexpr int LST = KS + 8;
  constexpr int NA = BM * CPR;
  constexpr int NB = BN * CPR;
  constexpr int ACH = (NA + 511) / 512;
  constexpr int BCH = (NB + 511) / 512;
  constexpr int MFR = BM / 32;
  constexpr int KK = KS / 32;

  __shared__ unsigned short sA[2][BM * LST];
  __shared__ unsigned short sB[2][BN * LST];

  const int tid = threadIdx.x;
  const int lane = tid & 63;
  const int wave = tid >> 6;
  const int wm = wave >> 2, wo = wave & 3;
  const int bm = blockIdx.x * BM;
  const int bo = blockIdx.y * BN;
  const int l15 = lane & 15;
  const int kg = (lane >> 4) * 8;

  f32x4 acc[MFR][2] = {};
  const unsigned short* As[3] = {A0, A1, A2};

  u16x8 ra0[ACH], rb0[BCH], ra1[ACH], rb1[BCH];

  auto issue = [&](int s, u16x8 (&ra)[ACH], u16x8 (&rb)[BCH]) {
    int p = s / NSP, k0 = (s % NSP) * KS;
    const unsigned short* __restrict__ A = As[p];
    const unsigned short* __restrict__ B = Wt + (size_t)p * O * FPAD;
#pragma unroll
    for (int c = 0; c < ACH; ++c) {
      int idx = tid + c * 512;
      if (NA % 512 == 0 || idx < NA) {
        int row = idx / CPR, ch = (idx % CPR) * 8;
        int gm = bm + row; if (gm >= M) gm = M - 1;   // clamp; stores guarded
        ra[c] = *(const u16x8*)(A + (size_t)gm * FPAD + k0 + ch);
      }
    }
#pragma unroll
    for (int c = 0; c < BCH; ++c) {
      int idx = tid + c * 512;
      if (NB % 512 == 0 || idx < NB) {
        int row = idx / CPR, ch = (idx % CPR) * 8;
        rb[c] = *(const u16x8*)(B + (size_t)(bo + row) * FPAD + k0 + ch);
      }
    }
  };

  auto lds_write = [&](int buf, u16x8 (&ra)[ACH], u16x8 (&rb)[BCH]) {
#pragma unroll
    for (int c = 0; c < ACH; ++c) {
      int idx = tid + c * 512;
      if (NA % 512 == 0 || idx < NA) {
        int row = idx / CPR, ch = (idx % CPR) * 8;
        *(u16x8*)&sA[buf][row * LST + ch] = ra[c];
      }
    }
#pragma unroll
    for (int c = 0; c < BCH; ++c) {
      int idx = tid + c * 512;
      if (NB % 512 == 0 || idx < NB) {
        int row = idx / CPR, ch = (idx % CPR) * 8;
        *(u16x8*)&sB[buf][row * LST + ch] = rb[c];
      }
    }
  };

  auto compute = [&](int buf) {
#pragma unroll
    for (int kk = 0; kk < KK; ++kk) {
      bf16x8 af[MFR], bfr[2];
#pragma unroll
      for (int mi = 0; mi < MFR; ++mi)
        af[mi] = *(const bf16x8*)&sA[buf][(wm * (BM / 2) + mi * 16 + l15) * LST + kk * 32 + kg];
#pragma unroll
      for (int ni = 0; ni < 2; ++ni)
        bfr[ni] = *(const bf16x8*)&sB[buf][(wo * 32 + ni * 16 + l15) * LST + kk * 32 + kg];
#pragma unroll
      for (int mi = 0; mi < MFR; ++mi)
#pragma unroll
        for (int ni = 0; ni < 2; ++ni)
          acc[mi][ni] = __builtin_amdgcn_mfma_f32_16x16x32_bf16(af[mi], bfr[ni], acc[mi][ni], 0, 0, 0);
    }
  };

  // prologue: steps 0,1 in flight; step 0 staged
  issue(0, ra0, rb0);
  issue(1, ra1, rb1);
  lds_write(0, ra0, rb0);
  __syncthreads();

  // even steps live in set0, odd steps in set1
#pragma unroll
  for (int s = 0; s < NSTEP; ++s) {
    if ((s & 1) == 0) {
      if (s + 2 < NSTEP) issue(s + 2, ra0, rb0);
      compute(s & 1);
      if (s + 1 < NSTEP) { lds_write((s + 1) & 1, ra1, rb1); __syncthreads(); }
    } else {
      if (s + 2 < NSTEP) issue(s + 2, ra1, rb1);
      compute(s & 1);
      if (s + 1 < NSTEP) { lds_write((s + 1) & 1, ra0, rb0); __syncthreads(); }
    }
  }

  // epilogue: bias + relu + precomputed-noise multiply (+ bf16 shadow)
  const int r0 = (lane >> 4) * 4;
#pragma unroll
  for (int mi = 0; mi < MFR; ++mi) {
#pragma unroll
    for (int r = 0; r < 4; ++r) {
      int gm = bm + wm * (BM / 2) + mi * 16 + r0 + r;
      if (gm >= M) continue;
#pragma unroll
      for (int ni = 0; ni < 2; ++ni) {
        int go = bo + wo * 32 + ni * 16 + l15;
        float vv = acc[mi][ni][r] + bias[go];
        vv = vv > 0.0f ? vv : 0.0f;
        float res = vv * noise[(size_t)gm * O + go];
        out[(size_t)gm * O + go] = res;
        if (outb) outb[(size_t)gm * obstride + go] = f2bf(res);
      }
    }
  }
}

// ---------------- host orchestration ----------------
extern "C" void kernel_launch(void* const* d_in, const int* in_sizes, int n_in,
                              void* d_out, int out_size, void* d_ws, size_t ws_size,
                              hipStream_t stream) {
  const float* v    = (const float*)d_in[0];
  const int*  edges = (const int*)d_in[1];
  const float* W1 = (const float*)d_in[2];
  const float* b1 = (const float*)d_in[3];
  const float* W2 = (const float*)d_in[4];
  const float* b2 = (const float*)d_in[5];
  const float* W3 = (const float*)d_in[6];
  const float* b3 = (const float*)d_in[7];
  float* out = (float*)d_out;

  const int N = in_sizes[0] / 86;
  const int E = in_sizes[1] / 2;
  const int* rows = edges;
  const int* cols = edges + E;

  // ---- ws carve (16B-aligned chunks) ----
  uintptr_t cur = (uintptr_t)d_ws;
  auto alloc = [&](size_t bytes) {
    cur = (cur + 15) & ~(uintptr_t)15;
    void* p = (void*)cur;
    cur += bytes;
    return p;
  };
  float2* ecv          = (float2*)alloc((size_t)E * 8);
  int* counts          = (int*)alloc((size_t)N * 4);
  int* degs            = (int*)alloc((size_t)N * 4);
  int* row_ptr         = (int*)alloc((size_t)(N + 1) * 4);
  int* cursor          = (int*)alloc((size_t)N * 4);
  unsigned short* tx1b = (unsigned short*)alloc((size_t)N * 256 * 2);
  unsigned short* tx2b = (unsigned short*)alloc((size_t)N * 256 * 2);
  unsigned short* vb   = (unsigned short*)alloc((size_t)N * 96 * 2);
  unsigned short* x1b  = (unsigned short*)alloc((size_t)N * 128 * 2);
  unsigned short* x2b  = (unsigned short*)alloc((size_t)N * 256 * 2);
  unsigned short* Wt   = (unsigned short*)alloc((size_t)3 * 512 * 256 * 2);
  float* nbuf          = (float*)alloc((size_t)N * 512 * 4);   // reused per layer

  float* x1 = out;
  float* x2 = x1 + (size_t)N * 128;
  float* x3 = x2 + (size_t)N * 256;

  // CSR build + norm
  hipMemsetAsync(counts, 0, (size_t)2 * N * sizeof(int), stream);
  count_kernel<<<(E + 255) / 256, 256, 0, stream>>>(rows, cols, counts, degs, E);
  scan_kernel<<<1, SCAN_T, 0, stream>>>(counts, row_ptr, cursor, N);
  fill_kernel<<<(E + 255) / 256, 256, 0, stream>>>(rows, cols, degs, cursor, ecv, E);
  vconv_kernel<<<(N * 96 + 255) / 256, 256, 0, stream>>>(v, vb, N);

  const int pblocks = (N + 3) / 4;

  // ---- layer 1: F=86 (pad 96), O=128; BM=64, KS=32 ----
  {
    wtrans_kernel<<<(3 * 128 * 96 + 255) / 256, 256, 0, stream>>>(W1, Wt, 86, 96, 128);
    int t4 = N * 128 / 4, h4 = t4 / 2;
    gather_prop<2, 0, 1><<<pblocks, 256, 0, stream>>>(row_ptr, ecv, vb, 96, nullptr, 0, tx1b, N, 86, 96, nbuf, 0, h4);
    gather_prop<2, 1, 1><<<pblocks, 256, 0, stream>>>(row_ptr, ecv, tx1b, 96, v, 86, tx2b, N, 86, 96, nbuf, h4, t4);
    dim3 g((N + 63) / 64, 1);
    gemm3_db<64, 96, 32><<<g, 512, 0, stream>>>(vb, tx1b, tx2b, Wt, b1, nbuf, N, 128, x1, x1b, 128);
  }
  // ---- layer 2: F=128, O=256; BM=128, KS=64 ----
  {
    wtrans_kernel<<<(3 * 256 * 128 + 255) / 256, 256, 0, stream>>>(W2, Wt, 128, 128, 256);
    int t4 = N * 256 / 4, h4 = t4 / 2;
    gather_prop<2, 0, 2><<<pblocks, 256, 0, stream>>>(row_ptr, ecv, x1b, 128, nullptr, 0, tx1b, N, 128, 128, nbuf, 0, h4);
    gather_prop<2, 1, 2><<<pblocks, 256, 0, stream>>>(row_ptr, ecv, tx1b, 128, x1, 128, tx2b, N, 128, 128, nbuf, h4, t4);
    dim3 g((N + 127) / 128, 2);
    gemm3_db<128, 128, 64><<<g, 512, 0, stream>>>(x1b, tx1b, tx2b, Wt, b2, nbuf, N, 256, x2, x2b, 256);
  }
  // ---- layer 3: F=256, O=512; BM=128, KS=64 ----
  {
    wtrans_kernel<<<(3 * 512 * 256 + 255) / 256, 256, 0, stream>>>(W3, Wt, 256, 256, 512);
    int t4 = N * 512 / 4, h4 = t4 / 2;
    gather_prop<4, 0, 3><<<pblocks, 256, 0, stream>>>(row_ptr, ecv, x2b, 256, nullptr, 0, tx1b, N, 256, 256, nbuf, 0, h4);
    gather_prop<4, 1, 3><<<pblocks, 256, 0, stream>>>(row_ptr, ecv, tx1b, 256, x2, 256, tx2b, N, 256, 256, nbuf, h4, t4);
    dim3 g((N + 127) / 128, 4);
    gemm3_db<128, 256, 64><<<g, 512, 0, stream>>>(x2b, tx1b, tx2b, Wt, b3, nbuf, N, 512, x3, nullptr, 0);
  }
}

// Round 11
// 360.739 us; speedup vs baseline: 1.1309x; 1.0266x over previous
//
#include <hip/hip_runtime.h>
#include <stdint.h>
#include <math.h>

#define DEV static __device__ __forceinline__

typedef __attribute__((ext_vector_type(8))) short bf16x8;
typedef __attribute__((ext_vector_type(4))) float f32x4;
typedef __attribute__((ext_vector_type(8))) unsigned short u16x8;

// ---------------- Threefry-2x32/20 (exact JAX schedule) ----------------
DEV uint32_t rotl32(uint32_t v, int d) { return (v << d) | (v >> (32 - d)); }

DEV void threefry2x32(uint32_t k0, uint32_t k1, uint32_t& x0, uint32_t& x1) {
  const uint32_t k2 = k0 ^ k1 ^ 0x1BD11BDAu;
  x0 += k0; x1 += k1;
#define TFR(R) { x0 += x1; x1 = rotl32(x1, R) ^ x0; }
  TFR(13) TFR(15) TFR(26) TFR(6)
  x0 += k1; x1 += k2 + 1u;
  TFR(17) TFR(29) TFR(16) TFR(24)
  x0 += k2; x1 += k0 + 2u;
  TFR(13) TFR(15) TFR(26) TFR(6)
  x0 += k0; x1 += k1 + 3u;
  TFR(17) TFR(29) TFR(16) TFR(24)
  x0 += k1; x1 += k2 + 4u;
  TFR(13) TFR(15) TFR(26) TFR(6)
  x0 += k2; x1 += k0 + 5u;
#undef TFR
}

// ---------------- erfinv (XLA f32 ErfInv, Giles 2012) ----------------
DEV float erfinv_f32(float x) {
  float w = -log1pf(-x * x);
  float p;
  if (w < 5.0f) {
    w -= 2.5f;
    p = 2.81022636e-08f;
    p = fmaf(p, w, 3.43273939e-07f);
    p = fmaf(p, w, -3.5233877e-06f);
    p = fmaf(p, w, -4.39150654e-06f);
    p = fmaf(p, w, 0.00021858087f);
    p = fmaf(p, w, -0.00125372503f);
    p = fmaf(p, w, -0.00417768164f);
    p = fmaf(p, w, 0.246640727f);
    p = fmaf(p, w, 1.50140941f);
  } else {
    w = sqrtf(w) - 3.0f;
    p = -0.000200214257f;
    p = fmaf(p, w, 0.000100950558f);
    p = fmaf(p, w, 0.00134934322f);
    p = fmaf(p, w, -0.00367342844f);
    p = fmaf(p, w, 0.00573950773f);
    p = fmaf(p, w, -0.0076224613f);
    p = fmaf(p, w, 0.00943887047f);
    p = fmaf(p, w, 1.00167406f);
    p = fmaf(p, w, 2.83297682f);
  }
  return p * x;
}

DEV float normal_from_bits(uint32_t bits) {
  float f = __uint_as_float((bits >> 9) | 0x3F800000u) - 1.0f;
  const float lo = -0.99999994f;            // nextafter(-1, 0) in f32
  float u = fmaf(f, 2.0f, lo);
  u = fmaxf(u, lo);
  return 1.41421356f * erfinv_f32(u);
}

DEV unsigned short f2bf(float f) {   // RTNE f32 -> bf16
  uint32_t u = __float_as_uint(f);
  uint32_t r = u + 0x7FFFu + ((u >> 16) & 1u);
  return (unsigned short)(r >> 16);
}

DEV float bf2f(uint32_t h) { return __uint_as_float(h << 16); }

DEV float4 noise4(uint32_t f0, uint32_t f1, uint32_t i4) {
  uint32_t base = i4 * 4u;
  float4 r;
  { uint32_t a = 0u, b = base + 0u; threefry2x32(f0, f1, a, b); r.x = normal_from_bits(a ^ b); }
  { uint32_t a = 0u, b = base + 1u; threefry2x32(f0, f1, a, b); r.y = normal_from_bits(a ^ b); }
  { uint32_t a = 0u, b = base + 2u; threefry2x32(f0, f1, a, b); r.z = normal_from_bits(a ^ b); }
  { uint32_t a = 0u, b = base + 3u; threefry2x32(f0, f1, a, b); r.w = normal_from_bits(a ^ b); }
  return r;
}

// ---------------- CSR build ----------------
__global__ void count_kernel(const int* __restrict__ rows, const int* __restrict__ cols,
                             int* __restrict__ counts, int* __restrict__ degs, int E) {
  int e = blockIdx.x * blockDim.x + threadIdx.x;
  if (e < E) {
    int r = rows[e];
    atomicAdd(&counts[r], 1);
    if (r != cols[e]) atomicAdd(&degs[r], 1);
  }
}

#define SCAN_T 1024
__global__ __launch_bounds__(SCAN_T) void scan_kernel(const int* __restrict__ counts,
                                                      int* __restrict__ row_ptr,
                                                      int* __restrict__ cursor, int N) {
  __shared__ int sa[SCAN_T], sb[SCAN_T];
  const int t = threadIdx.x;
  const int CH = (N + SCAN_T - 1) / SCAN_T;
  int base = t * CH;
  int psum = 0;
  for (int k = 0; k < CH; ++k) {
    int idx = base + k;
    if (idx < N) psum += counts[idx];
  }
  sa[t] = psum;
  __syncthreads();
  int* src = sa; int* dst = sb;
  for (int off = 1; off < SCAN_T; off <<= 1) {
    int v = src[t];
    if (t >= off) v += src[t - off];
    dst[t] = v;
    __syncthreads();
    int* tmp = src; src = dst; dst = tmp;
  }
  int running = src[t] - psum;
  for (int k = 0; k < CH; ++k) {
    int idx = base + k;
    if (idx < N) {
      row_ptr[idx] = running;
      cursor[idx] = running;
      running += counts[idx];
    }
  }
  if (t == SCAN_T - 1) row_ptr[N] = running;
}

__global__ void fill_kernel(const int* __restrict__ rows, const int* __restrict__ cols,
                            const int* __restrict__ degs, int* __restrict__ cursor,
                            float2* __restrict__ ecv, int E) {
  int e = blockIdx.x * blockDim.x + threadIdx.x;
  if (e < E) {
    int r = rows[e], c = cols[e];
    int dr = degs[r], dc = degs[c];
    float w = (r != c && dr > 0 && dc > 0) ? -rsqrtf((float)dr) * rsqrtf((float)dc) : 0.0f;
    int pos = atomicAdd(&cursor[r], 1);
    ecv[pos] = make_float2(__int_as_float(c), w);
  }
}

// ---------------- prep: vconv + all weight transposes in one kernel ----------------
__global__ void prep_kernel(const float* __restrict__ v,
                            const float* __restrict__ W1, const float* __restrict__ W2,
                            const float* __restrict__ W3,
                            unsigned short* __restrict__ vb, unsigned short* __restrict__ wt1,
                            unsigned short* __restrict__ wt2, unsigned short* __restrict__ wt3,
                            int N) {
  int i = blockIdx.x * 256 + threadIdx.x;
  int nv = N * 96;
  if (i < nv) {
    int r = i / 96, k = i % 96;
    vb[i] = (k < 86) ? f2bf(v[(size_t)r * 86 + k]) : (unsigned short)0;
    return;
  }
  i -= nv;
  if (i < 3 * 128 * 96) {               // wt1[p][o][k], F=86 pad 96, O=128
    int k = i % 96, o = (i / 96) % 128, p = i / (96 * 128);
    wt1[i] = (k < 86) ? f2bf(W1[((size_t)p * 86 + k) * 128 + o]) : (unsigned short)0;
    return;
  }
  i -= 3 * 128 * 96;
  if (i < 3 * 256 * 128) {              // wt2[p][o][k], F=128, O=256
    int k = i % 128, o = (i / 128) % 256, p = i / (128 * 256);
    wt2[i] = f2bf(W2[((size_t)p * 128 + k) * 256 + o]);
    return;
  }
  i -= 3 * 256 * 128;
  if (i < 3 * 512 * 256) {              // wt3[p][o][k], F=256, O=512
    int k = i % 256, o = (i / 256) % 512, p = i / (256 * 512);
    wt3[i] = f2bf(W3[((size_t)p * 256 + k) * 512 + o]);
  }
}

// ---------------- 8-bf16 row loader (16B/lane) ----------------
DEV void ld8(const unsigned short* __restrict__ base, size_t off, float* v) {
  uint4 u = *(const uint4*)(base + off);
  v[0] = bf2f(u.x & 0xffffu); v[1] = bf2f(u.x >> 16);
  v[2] = bf2f(u.y & 0xffffu); v[3] = bf2f(u.y >> 16);
  v[4] = bf2f(u.z & 0xffffu); v[5] = bf2f(u.z >> 16);
  v[6] = bf2f(u.w & 0xffffu); v[7] = bf2f(u.w >> 16);
}

// ---------------- propagation: NL nodes/wave, 16B/lane, + fused bf16 noise ----------------
// SUB=0: outb = bf16(P x);  SUB=1: outb = bf16(2*P x - xsub)
template <int LPN, int NL, int SUB, int FOLD>
__global__ __launch_bounds__(256) void gather_prop(
    const int* __restrict__ row_ptr, const float2* __restrict__ ecv,
    const unsigned short* __restrict__ xsrc, int sstride,
    const float* __restrict__ xsub, int substride, int F,
    unsigned short* __restrict__ outb, int N, int Fpad,
    unsigned short* __restrict__ nbuf, int n4_begin, int n4_end) {
  const int wave = threadIdx.x >> 6, lane = threadIdx.x & 63;
  const int sub = lane / LPN;
  const int fl = (lane - sub * LPN) * 8;
  const int node = (blockIdx.x * 4 + wave) * NL + sub;
  if (sub < NL && node < N) {
    float acc[8] = {};
    const int s = row_ptr[node], e = row_ptr[node + 1];
    int j = s;
    for (; j + 8 <= e; j += 8) {
      float2 cw[8];
      float vv[8][8];
#pragma unroll
      for (int q = 0; q < 8; ++q) cw[q] = ecv[j + q];
#pragma unroll
      for (int q = 0; q < 8; ++q)
        ld8(xsrc, (size_t)__float_as_int(cw[q].x) * sstride + fl, vv[q]);
#pragma unroll
      for (int q = 0; q < 8; ++q)
#pragma unroll
        for (int z = 0; z < 8; ++z) acc[z] = fmaf(cw[q].y, vv[q][z], acc[z]);
    }
    for (; j + 2 <= e; j += 2) {
      float2 cw[2];
      float vv[2][8];
#pragma unroll
      for (int q = 0; q < 2; ++q) cw[q] = ecv[j + q];
#pragma unroll
      for (int q = 0; q < 2; ++q)
        ld8(xsrc, (size_t)__float_as_int(cw[q].x) * sstride + fl, vv[q]);
#pragma unroll
      for (int q = 0; q < 2; ++q)
#pragma unroll
        for (int z = 0; z < 8; ++z) acc[z] = fmaf(cw[q].y, vv[q][z], acc[z]);
    }
    for (; j < e; ++j) {
      float2 cw = ecv[j];
      float vv[8];
      ld8(xsrc, (size_t)__float_as_int(cw.x) * sstride + fl, vv);
#pragma unroll
      for (int z = 0; z < 8; ++z) acc[z] = fmaf(cw.y, vv[z], acc[z]);
    }
    if (SUB) {
      const float* sb = xsub + (size_t)node * substride;
      if (fl + 8 <= F) {
        float4 a = *(const float4*)(sb + fl);
        float4 b2 = *(const float4*)(sb + fl + 4);
        acc[0] = fmaf(2.0f, acc[0], -a.x);  acc[1] = fmaf(2.0f, acc[1], -a.y);
        acc[2] = fmaf(2.0f, acc[2], -a.z);  acc[3] = fmaf(2.0f, acc[3], -a.w);
        acc[4] = fmaf(2.0f, acc[4], -b2.x); acc[5] = fmaf(2.0f, acc[5], -b2.y);
        acc[6] = fmaf(2.0f, acc[6], -b2.z); acc[7] = fmaf(2.0f, acc[7], -b2.w);
      } else {
#pragma unroll
        for (int z = 0; z < 8; ++z) {
          int f = fl + z;
          float sv = (f < F) ? sb[f] : 0.0f;
          acc[z] = fmaf(2.0f, acc[z], -sv);
        }
      }
    }
    uint4 u;
    u.x = (uint32_t)f2bf(acc[0]) | ((uint32_t)f2bf(acc[1]) << 16);
    u.y = (uint32_t)f2bf(acc[2]) | ((uint32_t)f2bf(acc[3]) << 16);
    u.z = (uint32_t)f2bf(acc[4]) | ((uint32_t)f2bf(acc[5]) << 16);
    u.w = (uint32_t)f2bf(acc[6]) | ((uint32_t)f2bf(acc[7]) << 16);
    *(uint4*)&outb[(size_t)node * Fpad + fl] = u;
  }
  // fused noise: grid-stride over assigned float4 range, stored as bf16
  uint32_t f0k = 0u, f1k = (uint32_t)FOLD;
  threefry2x32(0u, 42u, f0k, f1k);
  const int gstride = gridDim.x * 256;
  for (int i4 = n4_begin + blockIdx.x * 256 + (int)threadIdx.x; i4 < n4_end; i4 += gstride) {
    float4 r = noise4(f0k, f1k, (uint32_t)i4);
    uint2 u;
    u.x = (uint32_t)f2bf(r.x) | ((uint32_t)f2bf(r.y) << 16);
    u.y = (uint32_t)f2bf(r.z) | ((uint32_t)f2bf(r.w) << 16);
    *(uint2*)&nbuf[(size_t)i4 * 4] = u;
  }
}

// ---------------- double-buffered LDS MFMA GEMM, XCD-swizzled grid ----------------
// out = relu(A0@W0+A1@W1+A2@W2+b)*noise; 512 thr = 8 waves (2M x 4O);
// tile BM x 128; all O-blocks of an M-tile land on the same XCD (A-tile L2 reuse).
template <int BM, int FPAD, int KS, int OB>
__global__ __launch_bounds__(512, 4) void gemm3_db(
    const unsigned short* __restrict__ A0, const unsigned short* __restrict__ A1,
    const unsigned short* __restrict__ A2,
    const unsigned short* __restrict__ Wt, const float* __restrict__ bias,
    const unsigned short* __restrict__ noise,
    int M, int MT, int O, float* __restrict__ out, unsigned short* __restrict__ outb,
    int obstride) {
  constexpr int BN = 128;
  constexpr int NSP = FPAD / KS;
  constexpr int NSTEP = 3 * NSP;
  constexpr int CPR = KS / 8;
  constexpr int LST = KS + 8;
  constexpr int NA = BM * CPR;
  constexpr int NB = BN * CPR;
  constexpr int ACH = (NA + 511) / 512;
  constexpr int BCH = (NB + 511) / 512;
  constexpr int MFR = BM / 32;
  constexpr int KK = KS / 32;

  // XCD swizzle: flat -> (m-tile, o-block) with all o-blocks of an m-tile on one XCD
  const int flat = blockIdx.x;
  const int xcd = flat & 7, idx = flat >> 3;
  const int mtile = xcd + 8 * (idx / OB);
  const int obl = idx - (idx / OB) * OB;
  if (mtile >= MT) return;
  const int bm = mtile * BM;
  const int bo = obl * BN;

  __shared__ unsigned short sA[2][BM * LST];
  __shared__ unsigned short sB[2][BN * LST];

  const int tid = threadIdx.x;
  const int lane = tid & 63;
  const int wave = tid >> 6;
  const int wm = wave >> 2, wo = wave & 3;
  const int l15 = lane & 15;
  const int kg = (lane >> 4) * 8;

  f32x4 acc[MFR][2] = {};
  const unsigned short* As[3] = {A0, A1, A2};

  u16x8 ra0[ACH], rb0[BCH], ra1[ACH], rb1[BCH];

  auto issue = [&](int s, u16x8 (&ra)[ACH], u16x8 (&rb)[BCH]) {
    int p = s / NSP, k0 = (s % NSP) * KS;
    const unsigned short* __restrict__ A = As[p];
    const unsigned short* __restrict__ B = Wt + (size_t)p * O * FPAD;
#pragma unroll
    for (int c = 0; c < ACH; ++c) {
      int idx2 = tid + c * 512;
      if (NA % 512 == 0 || idx2 < NA) {
        int row = idx2 / CPR, ch = (idx2 % CPR) * 8;
        int gm = bm + row; if (gm >= M) gm = M - 1;   // clamp; stores guarded
        ra[c] = *(const u16x8*)(A + (size_t)gm * FPAD + k0 + ch);
      }
    }
#pragma unroll
    for (int c = 0; c < BCH; ++c) {
      int idx2 = tid + c * 512;
      if (NB % 512 == 0 || idx2 < NB) {
        int row = idx2 / CPR, ch = (idx2 % CPR) * 8;
        rb[c] = *(const u16x8*)(B + (size_t)(bo + row) * FPAD + k0 + ch);
      }
    }
  };

  auto lds_write = [&](int buf, u16x8 (&ra)[ACH], u16x8 (&rb)[BCH]) {
#pragma unroll
    for (int c = 0; c < ACH; ++c) {
      int idx2 = tid + c * 512;
      if (NA % 512 == 0 || idx2 < NA) {
        int row = idx2 / CPR, ch = (idx2 % CPR) * 8;
        *(u16x8*)&sA[buf][row * LST + ch] = ra[c];
      }
    }
#pragma unroll
    for (int c = 0; c < BCH; ++c) {
      int idx2 = tid + c * 512;
      if (NB % 512 == 0 || idx2 < NB) {
        int row = idx2 / CPR, ch = (idx2 % CPR) * 8;
        *(u16x8*)&sB[buf][row * LST + ch] = rb[c];
      }
    }
  };

  auto compute = [&](int buf) {
#pragma unroll
    for (int kk = 0; kk < KK; ++kk) {
      bf16x8 af[MFR], bfr[2];
#pragma unroll
      for (int mi = 0; mi < MFR; ++mi)
        af[mi] = *(const bf16x8*)&sA[buf][(wm * (BM / 2) + mi * 16 + l15) * LST + kk * 32 + kg];
#pragma unroll
      for (int ni = 0; ni < 2; ++ni)
        bfr[ni] = *(const bf16x8*)&sB[buf][(wo * 32 + ni * 16 + l15) * LST + kk * 32 + kg];
#pragma unroll
      for (int mi = 0; mi < MFR; ++mi)
#pragma unroll
        for (int ni = 0; ni < 2; ++ni)
          acc[mi][ni] = __builtin_amdgcn_mfma_f32_16x16x32_bf16(af[mi], bfr[ni], acc[mi][ni], 0, 0, 0);
    }
  };

  issue(0, ra0, rb0);
  issue(1, ra1, rb1);
  lds_write(0, ra0, rb0);
  __syncthreads();

#pragma unroll
  for (int s = 0; s < NSTEP; ++s) {
    if ((s & 1) == 0) {
      if (s + 2 < NSTEP) issue(s + 2, ra0, rb0);
      compute(s & 1);
      if (s + 1 < NSTEP) { lds_write((s + 1) & 1, ra1, rb1); __syncthreads(); }
    } else {
      if (s + 2 < NSTEP) issue(s + 2, ra1, rb1);
      compute(s & 1);
      if (s + 1 < NSTEP) { lds_write((s + 1) & 1, ra0, rb0); __syncthreads(); }
    }
  }

  // epilogue: bias + relu + bf16-noise multiply (+ bf16 shadow)
  const int r0 = (lane >> 4) * 4;
#pragma unroll
  for (int mi = 0; mi < MFR; ++mi) {
#pragma unroll
    for (int r = 0; r < 4; ++r) {
      int gm = bm + wm * (BM / 2) + mi * 16 + r0 + r;
      if (gm >= M) continue;
#pragma unroll
      for (int ni = 0; ni < 2; ++ni) {
        int go = bo + wo * 32 + ni * 16 + l15;
        float vv = acc[mi][ni][r] + bias[go];
        vv = vv > 0.0f ? vv : 0.0f;
        float res = vv * bf2f((uint32_t)noise[(size_t)gm * O + go]);
        out[(size_t)gm * O + go] = res;
        if (outb) outb[(size_t)gm * obstride + go] = f2bf(res);
      }
    }
  }
}

// ---------------- host orchestration ----------------
extern "C" void kernel_launch(void* const* d_in, const int* in_sizes, int n_in,
                              void* d_out, int out_size, void* d_ws, size_t ws_size,
                              hipStream_t stream) {
  const float* v    = (const float*)d_in[0];
  const int*  edges = (const int*)d_in[1];
  const float* W1 = (const float*)d_in[2];
  const float* b1 = (const float*)d_in[3];
  const float* W2 = (const float*)d_in[4];
  const float* b2 = (const float*)d_in[5];
  const float* W3 = (const float*)d_in[6];
  const float* b3 = (const float*)d_in[7];
  float* out = (float*)d_out;

  const int N = in_sizes[0] / 86;
  const int E = in_sizes[1] / 2;
  const int* rows = edges;
  const int* cols = edges + E;

  // ---- ws carve (16B-aligned chunks) ----
  uintptr_t cur = (uintptr_t)d_ws;
  auto alloc = [&](size_t bytes) {
    cur = (cur + 15) & ~(uintptr_t)15;
    void* p = (void*)cur;
    cur += bytes;
    return p;
  };
  float2* ecv          = (float2*)alloc((size_t)E * 8);
  int* counts          = (int*)alloc((size_t)N * 4);
  int* degs            = (int*)alloc((size_t)N * 4);
  int* row_ptr         = (int*)alloc((size_t)(N + 1) * 4);
  int* cursor          = (int*)alloc((size_t)N * 4);
  unsigned short* tx1b = (unsigned short*)alloc((size_t)N * 256 * 2);
  unsigned short* tx2b = (unsigned short*)alloc((size_t)N * 256 * 2);
  unsigned short* vb   = (unsigned short*)alloc((size_t)N * 96 * 2);
  unsigned short* x1b  = (unsigned short*)alloc((size_t)N * 128 * 2);
  unsigned short* x2b  = (unsigned short*)alloc((size_t)N * 256 * 2);
  unsigned short* wt1  = (unsigned short*)alloc((size_t)3 * 128 * 96 * 2);
  unsigned short* wt2  = (unsigned short*)alloc((size_t)3 * 256 * 128 * 2);
  unsigned short* wt3  = (unsigned short*)alloc((size_t)3 * 512 * 256 * 2);
  unsigned short* nbuf = (unsigned short*)alloc((size_t)N * 512 * 2);  // bf16 noise, reused

  float* x1 = out;
  float* x2 = x1 + (size_t)N * 128;
  float* x3 = x2 + (size_t)N * 256;

  // CSR build + prep
  hipMemsetAsync(counts, 0, (size_t)2 * N * sizeof(int), stream);
  count_kernel<<<(E + 255) / 256, 256, 0, stream>>>(rows, cols, counts, degs, E);
  scan_kernel<<<1, SCAN_T, 0, stream>>>(counts, row_ptr, cursor, N);
  fill_kernel<<<(E + 255) / 256, 256, 0, stream>>>(rows, cols, degs, cursor, ecv, E);
  {
    int total = N * 96 + 3 * 128 * 96 + 3 * 256 * 128 + 3 * 512 * 256;
    prep_kernel<<<(total + 255) / 256, 256, 0, stream>>>(v, W1, W2, W3, vb, wt1, wt2, wt3, N);
  }

  // ---- layer 1: F=86 (pad 96), O=128; prop LPN=12 NL=4; gemm BM=64 KS=32 OB=1 ----
  {
    int pb = (N + 15) / 16;
    int t4 = N * 128 / 4, h4 = t4 / 2;
    gather_prop<12, 4, 0, 1><<<pb, 256, 0, stream>>>(row_ptr, ecv, vb, 96, nullptr, 0, 86, tx1b, N, 96, nbuf, 0, h4);
    gather_prop<12, 4, 1, 1><<<pb, 256, 0, stream>>>(row_ptr, ecv, tx1b, 96, v, 86, 86, tx2b, N, 96, nbuf, h4, t4);
    int mt = (N + 63) / 64;
    int grid = 8 * ((mt + 7) / 8) * 1;
    gemm3_db<64, 96, 32, 1><<<grid, 512, 0, stream>>>(vb, tx1b, tx2b, wt1, b1, nbuf, N, mt, 128, x1, x1b, 128);
  }
  // ---- layer 2: F=128, O=256; prop LPN=16 NL=4; gemm BM=128 KS=64 OB=2 ----
  {
    int pb = (N + 15) / 16;
    int t4 = N * 256 / 4, h4 = t4 / 2;
    gather_prop<16, 4, 0, 2><<<pb, 256, 0, stream>>>(row_ptr, ecv, x1b, 128, nullptr, 0, 128, tx1b, N, 128, nbuf, 0, h4);
    gather_prop<16, 4, 1, 2><<<pb, 256, 0, stream>>>(row_ptr, ecv, tx1b, 128, x1, 128, 128, tx2b, N, 128, nbuf, h4, t4);
    int mt = (N + 127) / 128;
    int grid = 8 * ((mt + 7) / 8) * 2;
    gemm3_db<128, 128, 64, 2><<<grid, 512, 0, stream>>>(x1b, tx1b, tx2b, wt2, b2, nbuf, N, mt, 256, x2, x2b, 256);
  }
  // ---- layer 3: F=256, O=512; prop LPN=32 NL=2; gemm BM=128 KS=64 OB=4 ----
  {
    int pb = (N + 7) / 8;
    int t4 = N * 512 / 4, h4 = t4 / 2;
    gather_prop<32, 2, 0, 3><<<pb, 256, 0, stream>>>(row_ptr, ecv, x2b, 256, nullptr, 0, 256, tx1b, N, 256, nbuf, 0, h4);
    gather_prop<32, 2, 1, 3><<<pb, 256, 0, stream>>>(row_ptr, ecv, tx1b, 256, x2, 256, 256, tx2b, N, 256, nbuf, h4, t4);
    int mt = (N + 127) / 128;
    int grid = 8 * ((mt + 7) / 8) * 4;
    gemm3_db<128, 256, 64, 4><<<grid, 512, 0, stream>>>(x2b, tx1b, tx2b, wt3, b3, nbuf, N, mt, 512, x3, nullptr, 0);
  }
}